// Round 6
// baseline (195.600 us; speedup 1.0000x reference)
//
#include <hip/hip_runtime.h>

typedef unsigned short u16;
typedef __attribute__((ext_vector_type(4))) float f32x4;
typedef __attribute__((ext_vector_type(8))) short s16x8;

#define BM 128
#define BN 128
#define BK 32

__device__ inline float bf2f(u16 u) {
    unsigned v = ((unsigned)u) << 16;
    return __builtin_bit_cast(float, v);
}
__device__ inline u16 f2bf(float f) {
    unsigned u = __builtin_bit_cast(unsigned, f);
    unsigned r = (u + 0x7FFFu + ((u >> 16) & 1u)) >> 16;
    return (u16)r;
}

typedef const __attribute__((address_space(1))) void* gptr_t;
typedef __attribute__((address_space(3))) void* lptr_t;
__device__ inline void gload16(const u16* gp, u16* lp) {
    __builtin_amdgcn_global_load_lds((gptr_t)gp, (lptr_t)lp, 16, 0, 0);
}

// ---------------- K0: x f32 [8][256][6400] -> xT bf16 [8][6400][256] ----------------
__global__ __launch_bounds__(256) void transpose_x(const float* __restrict__ x,
                                                   u16* __restrict__ xT) {
    __shared__ u16 tile[64 * 258];
    int blk = blockIdx.x;              // 800 = 8 * 100
    int b = blk / 100, hw0 = (blk % 100) * 64;
    int t = threadIdx.x;
    int l = t & 63, w = t >> 6;
    const float* xb = x + (size_t)b * 256 * 6400 + hw0 + l;
#pragma unroll 4
    for (int k = 0; k < 64; ++k) {
        int c = w + k * 4;
        tile[l * 258 + c] = f2bf(xb[(size_t)c * 6400]);
    }
    __syncthreads();
    u16* outb = xT + ((size_t)b * 6400 + hw0) * 256;
#pragma unroll
    for (int i = 0; i < 8; ++i) {
        int hw = w * 16 + i * 2 + (l >> 5);
        int c = (l & 31) * 8;
        *(int4*)(outb + (size_t)hw * 256 + c) = *(const int4*)&tile[hw * 258 + c];
    }
}

// ---------------- prep: f32 weights -> bf16 (permuted) + f32 fused biases ----------------
__global__ __launch_bounds__(256) void prep(
    const float* __restrict__ stem_w,
    const float* __restrict__ cls_conv_w, const float* __restrict__ cls_conv_b,
    const float* __restrict__ reg_conv_w, const float* __restrict__ reg_conv_b,
    const float* __restrict__ cls_pred_w, const float* __restrict__ cls_pred_b,
    const float* __restrict__ reg_pred_w, const float* __restrict__ reg_pred_b,
    const float* __restrict__ obj_pred_w, const float* __restrict__ obj_pred_b,
    u16* __restrict__ Wsb, u16* __restrict__ Wc, u16* __restrict__ Wf,
    float* __restrict__ bc, float* __restrict__ bp, u16* __restrict__ zpage) {
    int i0 = blockIdx.x * 256 + threadIdx.x;
    int stride = gridDim.x * 256;
    for (int i = i0; i < 256 * 256; i += stride) Wsb[i] = f2bf(stem_w[i]);
    // Wc [512][2304] with k' = j*256 + c  <-  conv_w[o][c*9 + j]
    for (int i = i0; i < 512 * 2304; i += stride) {
        int o = i / 2304, kk = i % 2304;
        int j = kk >> 8, c = kk & 255;
        const float* src = (o < 256) ? (cls_conv_w + (size_t)o * 2304)
                                     : (reg_conv_w + (size_t)(o - 256) * 2304);
        Wc[i] = f2bf(src[c * 9 + j]);
    }
    // Wf [128][512]: rows 0-3 reg_pred (k 256..511), 4 obj, 5-84 cls (k 0..255), rest 0
    for (int i = i0; i < 128 * 512; i += stride) {
        int o = i >> 9, k = i & 511;
        float v = 0.f;
        if (o < 4)       { if (k >= 256) v = reg_pred_w[o * 256 + (k - 256)]; }
        else if (o == 4) { if (k >= 256) v = obj_pred_w[k - 256]; }
        else if (o < 85) { if (k < 256)  v = cls_pred_w[(o - 5) * 256 + k]; }
        Wf[i] = f2bf(v);
    }
    for (int i = i0; i < 512; i += stride)
        bc[i] = (i < 256) ? cls_conv_b[i] : reg_conv_b[i - 256];
    for (int i = i0; i < 128; i += stride) {
        float v = 0.f;
        if (i < 4) v = reg_pred_b[i];
        else if (i == 4) v = obj_pred_b[0];
        else if (i < 85) v = cls_pred_b[i - 5];
        bp[i] = v;
    }
    for (int i = i0; i < 256; i += stride) zpage[i] = 0;
}

// ---------------- rowoff: per (n, j) element offset into NHWC stem, or -1 ----------------
__global__ __launch_bounds__(256) void rowptr_prep(const int* __restrict__ idx,
                                                   int* __restrict__ rowoff) {
    int i = blockIdx.x * 256 + threadIdx.x;       // 147456 = 16384*9
    if (i >= 16384 * 9) return;
    int n = i / 9, j = i % 9;
    int b = idx[n * 3 + 0], y = idx[n * 3 + 1], x = idx[n * 3 + 2];
    int yy = y + j / 3 - 1;
    int xx = x + j % 3 - 1;
    rowoff[i] = ((unsigned)yy < 80u && (unsigned)xx < 80u)
                    ? (b * 6400 + yy * 80 + xx) * 256 : -1;
}

// ---------------- gemm_bt (verified): D[m,n] = epi(sum_k A[m,k]*B[n,k] + bias[n]) ----------
// EPI 0: silu, bf16 store, ldd = N.  EPI 1: plain, f32 store, only cols < storeN, ldd = storeN.
template <int EPI>
__global__ __launch_bounds__(256, 2) void gemm_bt(
    const u16* __restrict__ A, const u16* __restrict__ B,
    const float* __restrict__ bias, void* __restrict__ Dv,
    int K, int ldd, int storeN) {
    __shared__ __align__(16) u16 lA[BM * BK];
    __shared__ __align__(16) u16 lB[BN * BK];
    const int tid = threadIdx.x;
    const int lane = tid & 63;
    const int wid = tid >> 6;
    const int wm = wid >> 1, wn = wid & 1;
    const int m0 = blockIdx.x * BM;
    const int n0 = blockIdx.y * BN;

    const int srow = lane >> 2;
    const int scol = (lane & 3) * 8;
    const int arow = lane & 15;
    const int khalf = (lane >> 4) * 8;

    f32x4 acc[4][4] = {};

    for (int k0 = 0; k0 < K; k0 += BK) {
#pragma unroll
        for (int r = 0; r < 2; ++r) {
            int row = r * 64 + wid * 16 + srow;
            gload16(A + (size_t)(m0 + row) * K + k0 + scol, lA + r * 2048 + wid * 512);
            gload16(B + (size_t)(n0 + row) * K + k0 + scol, lB + r * 2048 + wid * 512);
        }
        __syncthreads();
        s16x8 af[4], bfr[4];
#pragma unroll
        for (int f = 0; f < 4; ++f) {
            af[f]  = *(const s16x8*)&lA[(wm * 64 + f * 16 + arow) * BK + khalf];
            bfr[f] = *(const s16x8*)&lB[(wn * 64 + f * 16 + arow) * BK + khalf];
        }
#pragma unroll
        for (int i = 0; i < 4; ++i)
#pragma unroll
            for (int j = 0; j < 4; ++j)
                acc[i][j] = __builtin_amdgcn_mfma_f32_16x16x32_bf16(af[i], bfr[j],
                                                                    acc[i][j], 0, 0, 0);
        __syncthreads();
    }

#pragma unroll
    for (int i = 0; i < 4; ++i) {
        int gr0 = m0 + wm * 64 + i * 16 + (lane >> 4) * 4;
#pragma unroll
        for (int j = 0; j < 4; ++j) {
            int gc = n0 + wn * 64 + j * 16 + (lane & 15);
            if (EPI == 1 && gc >= storeN) continue;
            float bb = bias[gc];
#pragma unroll
            for (int r = 0; r < 4; ++r) {
                float v = acc[i][j][r] + bb;
                if (EPI == 0) {
                    v = v / (1.0f + __expf(-v));
                    ((u16*)Dv)[(size_t)(gr0 + r) * ldd + gc] = f2bf(v);
                } else {
                    ((float*)Dv)[(size_t)(gr0 + r) * ldd + gc] = v;
                }
            }
        }
    }
}

// ---------------- K3 fused, single-wave reg-direct: no LDS, no barriers ----------------
// feat = silu( gather(stem)[m,:] @ Wc^T + bc ).  One wave per 64x64 output tile.
// A/B fragments loaded global->reg (16B/lane, 16 rows x 64B lines = coalesced),
// double-buffered in named register sets (static indices). rowoff prefetched 1 tap ahead.
__global__ __launch_bounds__(64, 2) void gemm_conv_rd(
    const u16* __restrict__ stem, const int* __restrict__ rowoff,
    const u16* __restrict__ zpage, const u16* __restrict__ B,
    const float* __restrict__ bias, u16* __restrict__ D) {
    const int lane = threadIdx.x;      // 0..63
    const int arow = lane & 15;
    const int khalf = lane >> 4;       // 0..3
    const int koff = khalf * 8;        // element offset within a 32-wide k slice
    const int m0 = blockIdx.x * 64;
    const int n0 = blockIdx.y * 64;

    f32x4 acc[4][4] = {};

    // per-lane rowoff for the 4 A-fragment rows, current tap + next tap
    int roC[4], roN[4];
#pragma unroll
    for (int f = 0; f < 4; ++f)
        roC[f] = rowoff[(m0 + f * 16 + arow) * 9 + 0];

    // per-lane base pointers
    const u16* bbase[4];
#pragma unroll
    for (int g = 0; g < 4; ++g)
        bbase[g] = B + (size_t)(n0 + g * 16 + arow) * 2304 + koff;

    s16x8 afA[2][4], bfA[2][4], afB[2][4], bfB[2][4];

#define LOAD_A(dst, ro, c0)                                                     \
    {                                                                           \
        _Pragma("unroll")                                                       \
        for (int f = 0; f < 4; ++f) {                                           \
            const u16* ap = (ro[f] < 0) ? zpage : (stem + ro[f]);               \
            _Pragma("unroll")                                                   \
            for (int ks = 0; ks < 2; ++ks)                                      \
                dst[ks][f] = *(const s16x8*)(ap + (c0) + ks * 32 + koff);       \
        }                                                                       \
    }
#define LOAD_B(dst, s)                                                          \
    {                                                                           \
        _Pragma("unroll")                                                       \
        for (int g = 0; g < 4; ++g)                                             \
            _Pragma("unroll")                                                   \
            for (int ks = 0; ks < 2; ++ks)                                      \
                dst[ks][g] = *(const s16x8*)(bbase[g] + (s) * 64 + ks * 32);    \
    }
#define COMP(af, bf)                                                            \
    {                                                                           \
        _Pragma("unroll")                                                       \
        for (int ks = 0; ks < 2; ++ks)                                          \
            _Pragma("unroll")                                                   \
            for (int i = 0; i < 4; ++i)                                         \
                _Pragma("unroll")                                               \
                for (int j = 0; j < 4; ++j)                                     \
                    acc[i][j] = __builtin_amdgcn_mfma_f32_16x16x32_bf16(        \
                        af[ks][i], bf[ks][j], acc[i][j], 0, 0, 0);              \
    }

    // prologue: step 0 (tap 0, c0=0) into buffer A
    LOAD_A(afA, roC, 0);
    LOAD_B(bfA, 0);

    for (int j = 0; j < 9; ++j) {
        // prefetch next tap's rowoff early (used 3 steps later)
        if (j < 8) {
#pragma unroll
            for (int f = 0; f < 4; ++f)
                roN[f] = rowoff[(m0 + f * 16 + arow) * 9 + j + 1];
        }
        // steps 4j .. 4j+3 (c0 = 0,64,128,192 within tap j); buffers alternate A,B,A,B
        LOAD_A(afB, roC, 64);  LOAD_B(bfB, 4 * j + 1);  COMP(afA, bfA);
        LOAD_A(afA, roC, 128); LOAD_B(bfA, 4 * j + 2);  COMP(afB, bfB);
        LOAD_A(afB, roC, 192); LOAD_B(bfB, 4 * j + 3);  COMP(afA, bfA);
        if (j < 8) { LOAD_A(afA, roN, 0); LOAD_B(bfA, 4 * j + 4); }
        COMP(afB, bfB);
#pragma unroll
        for (int f = 0; f < 4; ++f) roC[f] = roN[f];
    }
#undef LOAD_A
#undef LOAD_B
#undef COMP

#pragma unroll
    for (int i = 0; i < 4; ++i) {
        int gr0 = m0 + i * 16 + khalf * 4;
#pragma unroll
        for (int jj = 0; jj < 4; ++jj) {
            int gc = n0 + jj * 16 + arow;
            float bb = bias[gc];
#pragma unroll
            for (int r = 0; r < 4; ++r) {
                float v = acc[i][jj][r] + bb;
                v = v / (1.0f + __expf(-v));
                D[(size_t)(gr0 + r) * 512 + gc] = f2bf(v);
            }
        }
    }
}

extern "C" void kernel_launch(void* const* d_in, const int* in_sizes, int n_in,
                              void* d_out, int out_size, void* d_ws, size_t ws_size,
                              hipStream_t stream) {
    const float* x          = (const float*)d_in[0];
    const int*   idx        = (const int*)d_in[1];
    const float* stem_w     = (const float*)d_in[2];
    const float* stem_b     = (const float*)d_in[3];
    const float* cls_conv_w = (const float*)d_in[4];
    const float* cls_conv_b = (const float*)d_in[5];
    const float* reg_conv_w = (const float*)d_in[6];
    const float* reg_conv_b = (const float*)d_in[7];
    const float* cls_pred_w = (const float*)d_in[8];
    const float* cls_pred_b = (const float*)d_in[9];
    const float* reg_pred_w = (const float*)d_in[10];
    const float* reg_pred_b = (const float*)d_in[11];
    const float* obj_pred_w = (const float*)d_in[12];
    const float* obj_pred_b = (const float*)d_in[13];
    float* out = (float*)d_out;
    char* ws = (char*)d_ws;

    // ws layout (bytes), all 16B-aligned; total ~72.4 MB
    u16*  xT     = (u16*)(ws);                    // 8*6400*256*2  = 26,214,400
    u16*  stem   = (u16*)(ws + 26214400);         // 26,214,400 (NHWC bf16)
    u16*  feat   = (u16*)(ws + 52428800);         // 16384*512*2   = 16,777,216
    u16*  Wc     = (u16*)(ws + 69206016);         // 512*2304*2    = 2,359,296
    u16*  Wf     = (u16*)(ws + 71565312);         // 128*512*2     = 131,072
    u16*  Wsb    = (u16*)(ws + 71696384);         // 256*256*2     = 131,072
    int*  rowoff = (int*)(ws + 71827456);         // 16384*9*4     = 589,824
    u16*  zpage  = (u16*)(ws + 72417280);         // 512 B zero page
    float* bc    = (float*)(ws + 72417792);       // 2048
    float* bp    = (float*)(ws + 72419840);       // 512

    prep<<<1024, 256, 0, stream>>>(stem_w,
                                   cls_conv_w, cls_conv_b, reg_conv_w, reg_conv_b,
                                   cls_pred_w, cls_pred_b, reg_pred_w, reg_pred_b,
                                   obj_pred_w, obj_pred_b,
                                   Wsb, Wc, Wf, bc, bp, zpage);
    rowptr_prep<<<576, 256, 0, stream>>>(idx, rowoff);
    transpose_x<<<800, 256, 0, stream>>>(x, xT);
    // K1: stem = silu(xT @ stem_w^T + b)  -> NHWC bf16 [51200][256]
    gemm_bt<0><<<dim3(400, 2), 256, 0, stream>>>(xT, Wsb, stem_b, stem, 256, 256, 256);
    // K3 fused gather+conv: feat = silu(gather(stem) @ Wc^T + bc)  [16384][512]
    gemm_conv_rd<<<dim3(256, 8), 64, 0, stream>>>(stem, rowoff, zpage, Wc, bc, feat);
    // K4: out[n][p<85] = feat @ Wf^T + bp  (f32 store)
    gemm_bt<1><<<dim3(128, 1), 256, 0, stream>>>(feat, Wf, bp, out, 512, 85, 85);
}

// Round 7
// 100.600 us; speedup vs baseline: 1.9443x; 1.9443x over previous
//
#include <hip/hip_runtime.h>

typedef unsigned short u16;
typedef __attribute__((ext_vector_type(4))) float f32x4;
typedef __attribute__((ext_vector_type(8))) short s16x8;

#define BM 128
#define BN 128
#define BK 32

__device__ inline float bf2f(u16 u) {
    unsigned v = ((unsigned)u) << 16;
    return __builtin_bit_cast(float, v);
}
__device__ inline u16 f2bf(float f) {
    unsigned u = __builtin_bit_cast(unsigned, f);
    unsigned r = (u + 0x7FFFu + ((u >> 16) & 1u)) >> 16;
    return (u16)r;
}

typedef const __attribute__((address_space(1))) void* gptr_t;
typedef __attribute__((address_space(3))) void* lptr_t;
__device__ inline void gload16(const u16* gp, u16* lp) {
    __builtin_amdgcn_global_load_lds((gptr_t)gp, (lptr_t)lp, 16, 0, 0);
}

// ---------------- fused_pre: transpose + weight permutes + rowoff + biases ----------------
// Block-range dispatch; independent jobs run concurrently on different CUs.
//   [0,800)     : x f32 [8][256][6400] -> xT bf16 [8][6400][256] (LDS-staged)
//   [800,1312)  : Wc row o = blk-800   (k' = j*256+c permute, no divides)
//   [1312,1888) : rowoff (16384*9)
//   [1888,1952) : Wsb (stem_w -> bf16)
//   [1952,1984) : Wf (fused pred weight, zero-padded)
//   1984        : bc, bp, zpage
__global__ __launch_bounds__(256) void fused_pre(
    const float* __restrict__ x, const int* __restrict__ idx,
    const float* __restrict__ stem_w,
    const float* __restrict__ cls_conv_w, const float* __restrict__ cls_conv_b,
    const float* __restrict__ reg_conv_w, const float* __restrict__ reg_conv_b,
    const float* __restrict__ cls_pred_w, const float* __restrict__ cls_pred_b,
    const float* __restrict__ reg_pred_w, const float* __restrict__ reg_pred_b,
    const float* __restrict__ obj_pred_w, const float* __restrict__ obj_pred_b,
    u16* __restrict__ xT, u16* __restrict__ Wsb, u16* __restrict__ Wc,
    u16* __restrict__ Wf, int* __restrict__ rowoff,
    float* __restrict__ bc, float* __restrict__ bp, u16* __restrict__ zpage) {
    __shared__ u16 tile[64 * 258];
    const int blk = blockIdx.x;
    const int t = threadIdx.x;

    if (blk < 800) {                       // ---- transpose ----
        int b = blk / 100, hw0 = (blk % 100) * 64;
        int l = t & 63, w = t >> 6;
        const float* xb = x + (size_t)b * 256 * 6400 + hw0 + l;
#pragma unroll 4
        for (int k = 0; k < 64; ++k) {
            int c = w + k * 4;
            tile[l * 258 + c] = f2bf(xb[(size_t)c * 6400]);
        }
        __syncthreads();
        u16* outb = xT + ((size_t)b * 6400 + hw0) * 256;
#pragma unroll
        for (int i = 0; i < 8; ++i) {
            int hw = w * 16 + i * 2 + (l >> 5);
            int c = (l & 31) * 8;
            *(int4*)(outb + (size_t)hw * 256 + c) = *(const int4*)&tile[hw * 258 + c];
        }
    } else if (blk < 1312) {               // ---- Wc permute, one output row per block ----
        int o = blk - 800;
        const float* src = (o < 256) ? (cls_conv_w + (size_t)o * 2304)
                                     : (reg_conv_w + (size_t)(o - 256) * 2304);
        u16* dst = Wc + (size_t)o * 2304;
#pragma unroll
        for (int it = 0; it < 9; ++it) {
            int kk = it * 256 + t;
            int j = kk >> 8, c = kk & 255;
            dst[kk] = f2bf(src[c * 9 + j]);
        }
    } else if (blk < 1888) {               // ---- rowoff ----
        int i = (blk - 1312) * 256 + t;    // < 147456
        int n = i / 9, j = i % 9;
        int b = idx[n * 3 + 0], y = idx[n * 3 + 1], xx0 = idx[n * 3 + 2];
        int yy = y + j / 3 - 1;
        int xx = xx0 + j % 3 - 1;
        rowoff[i] = ((unsigned)yy < 80u && (unsigned)xx < 80u)
                        ? (b * 6400 + yy * 80 + xx) * 256 : -1;
    } else if (blk < 1952) {               // ---- Wsb ----
        int base = (blk - 1888) * 1024;
#pragma unroll
        for (int it = 0; it < 4; ++it) {
            int i = base + it * 256 + t;
            Wsb[i] = f2bf(stem_w[i]);
        }
    } else if (blk < 1984) {               // ---- Wf ----
        int base = (blk - 1952) * 2048;
#pragma unroll
        for (int it = 0; it < 8; ++it) {
            int i = base + it * 256 + t;
            int o = i >> 9, k = i & 511;
            float v = 0.f;
            if (o < 4)       { if (k >= 256) v = reg_pred_w[o * 256 + (k - 256)]; }
            else if (o == 4) { if (k >= 256) v = obj_pred_w[k - 256]; }
            else if (o < 85) { if (k < 256)  v = cls_pred_w[(o - 5) * 256 + k]; }
            Wf[i] = f2bf(v);
        }
    } else {                               // ---- biases + zero page ----
        for (int i = t; i < 512; i += 256)
            bc[i] = (i < 256) ? cls_conv_b[i] : reg_conv_b[i - 256];
        if (t < 128) {
            float v = 0.f;
            if (t < 4) v = reg_pred_b[t];
            else if (t == 4) v = obj_pred_b[0];
            else if (t < 85) v = cls_pred_b[t - 5];
            bp[t] = v;
        }
        zpage[t] = 0;
    }
}

// ---------------- gemm_bt (verified): D[m,n] = epi(sum_k A[m,k]*B[n,k] + bias[n]) ----------
// EPI 0: silu, bf16 store, ldd = N.
template <int EPI>
__global__ __launch_bounds__(256, 2) void gemm_bt(
    const u16* __restrict__ A, const u16* __restrict__ B,
    const float* __restrict__ bias, void* __restrict__ Dv,
    int K, int ldd, int storeN) {
    __shared__ __align__(16) u16 lA[BM * BK];
    __shared__ __align__(16) u16 lB[BN * BK];
    const int tid = threadIdx.x;
    const int lane = tid & 63;
    const int wid = tid >> 6;
    const int wm = wid >> 1, wn = wid & 1;
    const int m0 = blockIdx.x * BM;
    const int n0 = blockIdx.y * BN;

    const int srow = lane >> 2;
    const int scol = (lane & 3) * 8;
    const int arow = lane & 15;
    const int khalf = (lane >> 4) * 8;

    f32x4 acc[4][4] = {};

    for (int k0 = 0; k0 < K; k0 += BK) {
#pragma unroll
        for (int r = 0; r < 2; ++r) {
            int row = r * 64 + wid * 16 + srow;
            gload16(A + (size_t)(m0 + row) * K + k0 + scol, lA + r * 2048 + wid * 512);
            gload16(B + (size_t)(n0 + row) * K + k0 + scol, lB + r * 2048 + wid * 512);
        }
        __syncthreads();
        s16x8 af[4], bfr[4];
#pragma unroll
        for (int f = 0; f < 4; ++f) {
            af[f]  = *(const s16x8*)&lA[(wm * 64 + f * 16 + arow) * BK + khalf];
            bfr[f] = *(const s16x8*)&lB[(wn * 64 + f * 16 + arow) * BK + khalf];
        }
#pragma unroll
        for (int i = 0; i < 4; ++i)
#pragma unroll
            for (int j = 0; j < 4; ++j)
                acc[i][j] = __builtin_amdgcn_mfma_f32_16x16x32_bf16(af[i], bfr[j],
                                                                    acc[i][j], 0, 0, 0);
        __syncthreads();
    }

#pragma unroll
    for (int i = 0; i < 4; ++i) {
        int gr0 = m0 + wm * 64 + i * 16 + (lane >> 4) * 4;
#pragma unroll
        for (int j = 0; j < 4; ++j) {
            int gc = n0 + wn * 64 + j * 16 + (lane & 15);
            if (EPI == 1 && gc >= storeN) continue;
            float bb = bias[gc];
#pragma unroll
            for (int r = 0; r < 4; ++r) {
                float v = acc[i][j][r] + bb;
                if (EPI == 0) {
                    v = v / (1.0f + __expf(-v));
                    ((u16*)Dv)[(size_t)(gr0 + r) * ldd + gc] = f2bf(v);
                } else {
                    ((float*)Dv)[(size_t)(gr0 + r) * ldd + gc] = v;
                }
            }
        }
    }
}

// ---------------- K3 fused (round-4 verified): feat = silu(gather(stem) @ Wc^T + bc) ------
// BM=128, BN=64, BK=64 -> grid (128,8) = 1024 blocks = 4 blocks/CU.
__global__ __launch_bounds__(256, 4) void gemm_conv(
    const u16* __restrict__ stem, const int* __restrict__ rowoff,
    const u16* __restrict__ zpage, const u16* __restrict__ B,
    const float* __restrict__ bias, u16* __restrict__ D) {
    __shared__ __align__(16) u16 lA[128 * 64];
    __shared__ __align__(16) u16 lB[64 * 64];
    const int tid = threadIdx.x;
    const int lane = tid & 63;
    const int wid = tid >> 6;
    const int wm = wid >> 1, wn = wid & 1;
    const int m0 = blockIdx.x * 128;
    const int n0 = blockIdx.y * 64;

    const int srw = lane >> 3;          // staging row within 8-row group (= row&7)
    const int cc  = lane & 7;           // staging chunk slot (16B units)
    const int arow = lane & 15;
    const int khi  = lane >> 4;         // 0..3

    f32x4 acc[4][2] = {};

    for (int k0 = 0; k0 < 2304; k0 += 64) {
        const int j  = k0 >> 8;         // kernel tap 0..8
        const int c0 = k0 & 255;        // channel base within tap
        const int gch = (cc ^ srw) * 8; // inverse-swizzled source chunk
#pragma unroll
        for (int r = 0; r < 4; ++r) {
            int row = r * 32 + wid * 8 + srw;          // 0..127 ; row&7 == srw
            int roff = rowoff[(m0 + row) * 9 + j];
            const u16* srcA = (roff < 0) ? (zpage + gch)
                                         : (stem + roff + c0 + gch);
            gload16(srcA, lA + (r * 32 + wid * 8) * 64);
        }
#pragma unroll
        for (int r = 0; r < 2; ++r) {
            int row = r * 32 + wid * 8 + srw;          // 0..63
            gload16(B + (size_t)(n0 + row) * 2304 + k0 + gch,
                    lB + (r * 32 + wid * 8) * 64);
        }
        __syncthreads();
        s16x8 af[2][4], bfr[2][2];
        const int sa = arow & 7;
#pragma unroll
        for (int f = 0; f < 4; ++f) {
            int ra = (wm * 64 + f * 16 + arow) * 64;
#pragma unroll
            for (int ks = 0; ks < 2; ++ks) {
                int q = ks * 4 + khi;
                af[ks][f] = *(const s16x8*)&lA[ra + ((q ^ sa) << 3)];
            }
        }
#pragma unroll
        for (int jj = 0; jj < 2; ++jj) {
            int rb = (wn * 32 + jj * 16 + arow) * 64;
#pragma unroll
            for (int ks = 0; ks < 2; ++ks) {
                int q = ks * 4 + khi;
                bfr[ks][jj] = *(const s16x8*)&lB[rb + ((q ^ sa) << 3)];
            }
        }
#pragma unroll
        for (int ks = 0; ks < 2; ++ks)
#pragma unroll
            for (int i = 0; i < 4; ++i)
#pragma unroll
                for (int jj = 0; jj < 2; ++jj)
                    acc[i][jj] = __builtin_amdgcn_mfma_f32_16x16x32_bf16(
                        af[ks][i], bfr[ks][jj], acc[i][jj], 0, 0, 0);
        __syncthreads();
    }

#pragma unroll
    for (int i = 0; i < 4; ++i) {
        int gr0 = m0 + wm * 64 + i * 16 + khi * 4;
#pragma unroll
        for (int jj = 0; jj < 2; ++jj) {
            int gc = n0 + wn * 32 + jj * 16 + arow;
            float bb = bias[gc];
#pragma unroll
            for (int r = 0; r < 4; ++r) {
                float v = acc[i][jj][r] + bb;
                v = v / (1.0f + __expf(-v));
                D[(size_t)(gr0 + r) * 512 + gc] = f2bf(v);
            }
        }
    }
}

// ---------------- K4: out[m, p<85] = feat[m,:] @ Wf^T + bp  (f32, ldd=85) ----------------
// BM=64, BN=64, BK=64, wave tile 32x32 -> grid (256,2) = 512 blocks = 2 blocks/CU.
__global__ __launch_bounds__(256, 4) void gemm_pred(
    const u16* __restrict__ A, const u16* __restrict__ B,
    const float* __restrict__ bias, float* __restrict__ D) {
    __shared__ __align__(16) u16 lA[64 * 64];
    __shared__ __align__(16) u16 lB[64 * 64];
    const int tid = threadIdx.x;
    const int lane = tid & 63;
    const int wid = tid >> 6;
    const int wm = wid >> 1, wn = wid & 1;
    const int m0 = blockIdx.x * 64;
    const int n0 = blockIdx.y * 64;

    const int srw = lane >> 3;
    const int cc  = lane & 7;
    const int arow = lane & 15;
    const int khi  = lane >> 4;

    f32x4 acc[2][2] = {};

    for (int k0 = 0; k0 < 512; k0 += 64) {
        const int gch = (cc ^ srw) * 8;
#pragma unroll
        for (int r = 0; r < 2; ++r) {
            int row = r * 32 + wid * 8 + srw;          // 0..63
            gload16(A + (size_t)(m0 + row) * 512 + k0 + gch,
                    lA + (r * 32 + wid * 8) * 64);
            gload16(B + (size_t)(n0 + row) * 512 + k0 + gch,
                    lB + (r * 32 + wid * 8) * 64);
        }
        __syncthreads();
        s16x8 af[2][2], bfr[2][2];
        const int sa = arow & 7;
#pragma unroll
        for (int f = 0; f < 2; ++f) {
            int ra = (wm * 32 + f * 16 + arow) * 64;
            int rb = (wn * 32 + f * 16 + arow) * 64;
#pragma unroll
            for (int ks = 0; ks < 2; ++ks) {
                int q = ks * 4 + khi;
                af[ks][f]  = *(const s16x8*)&lA[ra + ((q ^ sa) << 3)];
                bfr[ks][f] = *(const s16x8*)&lB[rb + ((q ^ sa) << 3)];
            }
        }
#pragma unroll
        for (int ks = 0; ks < 2; ++ks)
#pragma unroll
            for (int i = 0; i < 2; ++i)
#pragma unroll
                for (int jj = 0; jj < 2; ++jj)
                    acc[i][jj] = __builtin_amdgcn_mfma_f32_16x16x32_bf16(
                        af[ks][i], bfr[ks][jj], acc[i][jj], 0, 0, 0);
        __syncthreads();
    }

#pragma unroll
    for (int i = 0; i < 2; ++i) {
        int gr0 = m0 + wm * 32 + i * 16 + khi * 4;
#pragma unroll
        for (int jj = 0; jj < 2; ++jj) {
            int gc = n0 + wn * 32 + jj * 16 + arow;
            if (gc >= 85) continue;
            float bb = bias[gc];
#pragma unroll
            for (int r = 0; r < 4; ++r)
                D[(size_t)(gr0 + r) * 85 + gc] = acc[i][jj][r] + bb;
        }
    }
}

extern "C" void kernel_launch(void* const* d_in, const int* in_sizes, int n_in,
                              void* d_out, int out_size, void* d_ws, size_t ws_size,
                              hipStream_t stream) {
    const float* x          = (const float*)d_in[0];
    const int*   idx        = (const int*)d_in[1];
    const float* stem_w     = (const float*)d_in[2];
    const float* stem_b     = (const float*)d_in[3];
    const float* cls_conv_w = (const float*)d_in[4];
    const float* cls_conv_b = (const float*)d_in[5];
    const float* cls_pred_w = (const float*)d_in[8];
    const float* cls_pred_b = (const float*)d_in[9];
    const float* reg_conv_w = (const float*)d_in[6];
    const float* reg_conv_b = (const float*)d_in[7];
    const float* reg_pred_w = (const float*)d_in[10];
    const float* reg_pred_b = (const float*)d_in[11];
    const float* obj_pred_w = (const float*)d_in[12];
    const float* obj_pred_b = (const float*)d_in[13];
    float* out = (float*)d_out;
    char* ws = (char*)d_ws;

    // ws layout (bytes), all 16B-aligned; total ~72.4 MB
    u16*  xT     = (u16*)(ws);                    // 8*6400*256*2  = 26,214,400
    u16*  stem   = (u16*)(ws + 26214400);         // 26,214,400 (NHWC bf16)
    u16*  feat   = (u16*)(ws + 52428800);         // 16384*512*2   = 16,777,216
    u16*  Wc     = (u16*)(ws + 69206016);         // 512*2304*2    = 2,359,296
    u16*  Wf     = (u16*)(ws + 71565312);         // 128*512*2     = 131,072
    u16*  Wsb    = (u16*)(ws + 71696384);         // 256*256*2     = 131,072
    int*  rowoff = (int*)(ws + 71827456);         // 16384*9*4     = 589,824
    u16*  zpage  = (u16*)(ws + 72417280);         // 512 B zero page
    float* bc    = (float*)(ws + 72417792);       // 2048
    float* bp    = (float*)(ws + 72419840);       // 512

    fused_pre<<<1985, 256, 0, stream>>>(x, idx, stem_w,
                                        cls_conv_w, cls_conv_b, reg_conv_w, reg_conv_b,
                                        cls_pred_w, cls_pred_b, reg_pred_w, reg_pred_b,
                                        obj_pred_w, obj_pred_b,
                                        xT, Wsb, Wc, Wf, rowoff, bc, bp, zpage);
    // K1: stem = silu(xT @ stem_w^T + b)  -> NHWC bf16 [51200][256]
    gemm_bt<0><<<dim3(400, 2), 256, 0, stream>>>(xT, Wsb, stem_b, stem, 256, 256, 256);
    // K3 fused gather+conv: feat = silu(gather(stem) @ Wc^T + bc)  [16384][512]
    gemm_conv<<<dim3(128, 8), 256, 0, stream>>>(stem, rowoff, zpage, Wc, bc, feat);
    // K4: out[n][p<85] = feat @ Wf^T + bp  (f32 store)
    gemm_pred<<<dim3(256, 2), 256, 0, stream>>>(feat, Wf, bp, out);
}